// Round 8
// baseline (319.245 us; speedup 1.0000x reference)
//
#include <hip/hip_runtime.h>

typedef __attribute__((ext_vector_type(4))) float  f32x4;
typedef __attribute__((ext_vector_type(8))) short  short8;
typedef __attribute__((ext_vector_type(4))) short  short4v;

#define M_TOK 8192
#define N_OUT 4096
#define K_IN  4096
#define NT32  128         // K_IN / 32

typedef const __attribute__((address_space(1))) void* gp_t;
typedef __attribute__((address_space(3))) void* lp_t;
__device__ __forceinline__ void gl_lds16(const void* g, void* l) {
    __builtin_amdgcn_global_load_lds((gp_t)g, (lp_t)l, 16, 0, 0);
}

// ---------------- pre-pass 1: x fp32 -> bf16 ----------------
__global__ __launch_bounds__(256)
void cvt_x(const float* __restrict__ x, unsigned short* __restrict__ xb) {
    const size_t i = ((size_t)blockIdx.x * 256 + threadIdx.x) * 8;
    f32x4 a = *(const f32x4*)(x + i);
    f32x4 b = *(const f32x4*)(x + i + 4);
    union { short8 v; __bf16 h[8]; } u;
    u.h[0] = (__bf16)a.x; u.h[1] = (__bf16)a.y; u.h[2] = (__bf16)a.z; u.h[3] = (__bf16)a.w;
    u.h[4] = (__bf16)b.x; u.h[5] = (__bf16)b.y; u.h[6] = (__bf16)b.z; u.h[7] = (__bf16)b.w;
    *(short8*)(xb + i) = u.v;
}

// ---------------- pre-pass 2: dequant qweight -> Wt[n][k] bf16 (transposed) ----------------
__global__ __launch_bounds__(256)
void dequant_w(const int* __restrict__ qweight, const int* __restrict__ qzeros,
               const float* __restrict__ scales, unsigned short* __restrict__ Wt) {
    const int k0 = blockIdx.x * 64;
    const int n0 = blockIdx.y * 64;
    const int t  = threadIdx.x;
    const int n  = t & 63;
    const int pl = t >> 6;
    const int g  = k0 >> 7;
    const int ncol = n0 + n;

    const float scale = scales[g * N_OUT + ncol];
    const int qz  = qzeros[g * (N_OUT / 8) + (ncol >> 3)];
    const int zp1 = ((qz >> ((ncol & 7) * 4)) & 0xF) + 1;
    const float zs = -(float)zp1 * scale;

    __shared__ unsigned short wt[64][80];

    const int p0 = k0 >> 3;
    #pragma unroll
    for (int i = 0; i < 2; ++i) {
        const int p_local = pl + i * 4;
        const int q = qweight[(size_t)(p0 + p_local) * N_OUT + ncol];
        union { short8 v; __bf16 h[8]; } u;
        #pragma unroll
        for (int j = 0; j < 8; ++j)
            u.h[j] = (__bf16)fmaf((float)((q >> (4 * j)) & 0xF), scale, zs);
        *(short8*)(&wt[n][8 * p_local]) = u.v;
    }
    __syncthreads();

    #pragma unroll
    for (int it = 0; it < 2; ++it) {
        const int row   = (t >> 3) + 32 * it;
        const int chunk = t & 7;
        short8 v = *(const short8*)(&wt[row][chunk * 8]);
        *(short8*)(Wt + (size_t)(n0 + row) * K_IN + k0 + chunk * 8) = v;
    }
}

// ---------------- main GEMM: 256x128 tile, BK=32, triple-buffer, 2 blocks/CU ----------------
// LDS: A bufs 3 x 16KB at 0/16K/32K ; B bufs 3 x 8KB at 48K + 0/8K/16K. Total 72KB.
__global__ __launch_bounds__(512, 4)
void gemm_bf16_occ(const unsigned short* __restrict__ xb,
                   const unsigned short* __restrict__ Wt,
                   const float* __restrict__ bias,
                   float* __restrict__ out)
{
    const int tid  = threadIdx.x;
    const int lane = tid & 63;
    const int wid  = tid >> 6;        // 0..7
    const int wm   = wid >> 1;        // 0..3 (64-row slab)
    const int wn   = wid & 1;         // 0..1 (64-col slab)

    // XCD swizzle: nwg = 1024, 1024 % 8 == 0 -> simple form bijective
    const int bid = blockIdx.x;
    const int swz = (bid & 7) * 128 + (bid >> 3);
    const int m0 = (swz >> 5) * 256;  // 32 m-tiles
    const int n0 = (swz & 31) * 128;  // 32 n-tiles

    __shared__ __align__(16) unsigned char lds[73728];

    f32x4 acc[4][4];                  // [mi][ni], wave tile 64x64
    #pragma unroll
    for (int i = 0; i < 4; ++i)
        #pragma unroll
        for (int j = 0; j < 4; ++j)
            acc[i][j] = f32x4{0.f, 0.f, 0.f, 0.f};

    // ---- staging constants ----
    // thread t -> row t>>2 (0..127), slot t&3 (16B slots of a 64B row); source slot
    // pre-swizzled so LDS dest stays linear: ss = (t&3) ^ ((row>>1)&3) = (t&3)^((t>>3)&3)
    const int sw8    = ((tid & 3) ^ ((tid >> 3) & 3)) * 8;   // source offset in bf16 elems
    const int srow   = tid >> 2;                             // 0..127
    const size_t a_src0 = (size_t)(m0 + srow) * K_IN + sw8;
    const size_t a_src1 = (size_t)(m0 + 128 + srow) * K_IN + sw8;
    const size_t b_src  = (size_t)(n0 + srow) * K_IN + sw8;
    const int dstb = tid * 16;

    // ---- fragment-read constants ----
    // row = slab + frag*16 + (lane&15); byte col = ((lane>>4) ^ ((row>>1)&3))<<4,
    // and (row>>1)&3 == (lane>>1)&3 (slab/frag are multiples of 16).
    const int rcol = (((lane >> 4)) ^ ((lane >> 1) & 3)) << 4;
    const int abase = (wm * 64 + (lane & 15)) * 64 + rcol;   // + mi*1024 + ABUF
    const int bbase = (wn * 64 + (lane & 15)) * 64 + rcol;   // + ni*1024 + BBUF(48K)

    short8 af[4], bf[4];

#define ABUF(S) ((S) * 16384)
#define BBUF(S) (49152 + (S) * 8192)

#define STAGE(SEL, KT) do { \
    gl_lds16(xb + a_src0 + (KT) * 32, lds + ABUF(SEL) + dstb); \
    gl_lds16(xb + a_src1 + (KT) * 32, lds + ABUF(SEL) + 8192 + dstb); \
    gl_lds16(Wt + b_src  + (KT) * 32, lds + BBUF(SEL) + dstb); } while (0)

    // prologue: tile 0 -> buf0, tile 1 -> buf1
    STAGE(0, 0);
    asm volatile("" ::: "memory");
    STAGE(1, 1);
    asm volatile("s_waitcnt vmcnt(3)" ::: "memory");   // tile 0 landed (tile 1 in flight)
    __builtin_amdgcn_s_barrier();

    int cbuf = 0;      // buffer holding tile kt
    int sbuf = 2;      // buffer to stage tile kt+2 into
    const unsigned char* lp = lds;

    #pragma unroll 1
    for (int kt = 0; kt < NT32; ++kt) {
        const int aoff = ABUF(cbuf);
        const int boff = BBUF(cbuf);
        // reads for THIS tile (covered by previous iteration's rally)
        #pragma unroll
        for (int mi = 0; mi < 4; ++mi)
            af[mi] = *(const short8*)(lp + aoff + abase + mi * 1024);
        #pragma unroll
        for (int ni = 0; ni < 4; ++ni)
            bf[ni] = *(const short8*)(lp + boff + bbase + ni * 1024);
        asm volatile("" ::: "memory");
        // stage tile kt+2 (wraps harmlessly at the tail; keeps vmcnt exact)
        STAGE(sbuf, (kt + 2) & (NT32 - 1));
        // rally: tile kt+1's 3 units are the ONLY ones allowed outstanding besides
        // the 3 just issued -> wait to 3 leaves kt+1 possibly in flight, kt+1's were
        // issued last iter; tile kt+1 must land before NEXT iter's reads:
        asm volatile("s_waitcnt vmcnt(3)" ::: "memory");
        __builtin_amdgcn_s_barrier();
        asm volatile("s_waitcnt lgkmcnt(0)" ::: "memory");
        __builtin_amdgcn_sched_barrier(0);
        __builtin_amdgcn_s_setprio(1);
        #pragma unroll
        for (int mi = 0; mi < 4; ++mi)
            #pragma unroll
            for (int ni = 0; ni < 4; ++ni)
                acc[mi][ni] = __builtin_amdgcn_mfma_f32_16x16x32_bf16(
                    af[mi], bf[ni], acc[mi][ni], 0, 0, 0);
        __builtin_amdgcn_s_setprio(0);
        cbuf = (cbuf == 2) ? 0 : cbuf + 1;
        sbuf = (sbuf == 2) ? 0 : sbuf + 1;
    }

#undef STAGE
#undef ABUF
#undef BBUF

    // epilogue: D col = lane&15 (+16*ni), row = (lane>>4)*4 + r (+16*mi)
    const int col_base = n0 + wn * 64 + (lane & 15);
    const int row_base = m0 + wm * 64 + (lane >> 4) * 4;
    #pragma unroll
    for (int ni = 0; ni < 4; ++ni) {
        const int col = col_base + ni * 16;
        const float bv = bias[col];
        #pragma unroll
        for (int mi = 0; mi < 4; ++mi) {
            #pragma unroll
            for (int r = 0; r < 4; ++r) {
                const int row = row_base + mi * 16 + r;
                out[(size_t)row * N_OUT + col] = acc[mi][ni][r] + bv;
            }
        }
    }
}

// ---------------- fallback: fused kernel (if ws too small) ----------------
__global__ __launch_bounds__(256, 2)
void gptq_gemm_fused(const float* __restrict__ x,
                     const int*   __restrict__ qweight,
                     const int*   __restrict__ qzeros,
                     const float* __restrict__ scales,
                     const float* __restrict__ bias,
                     float*       __restrict__ out)
{
    const int tid  = threadIdx.x;
    const int lane = tid & 63;
    const int wid  = tid >> 6;
    const int wm   = wid >> 1;
    const int wn   = wid & 1;
    const int m0 = blockIdx.y * 128;
    const int n0 = blockIdx.x * 128;

    __shared__ __align__(16) unsigned char lds[32768];
    unsigned char* Ab = lds;
    unsigned char* Bb = lds + 16384;

    const int ar  = tid >> 4;
    const int ac4 = (tid & 15) * 4;
    const int bnn = tid & 127;
    const int bph = tid >> 7;
    const int ncol = n0 + bnn;

    f32x4 a_reg[8];
    int   q_reg[4];
    float scale_r = 0.f, zs_r = 0.f;

    f32x4 acc[4][4];
    #pragma unroll
    for (int i = 0; i < 4; ++i)
        #pragma unroll
        for (int j = 0; j < 4; ++j)
            acc[i][j] = f32x4{0.f, 0.f, 0.f, 0.f};

    auto load_tile = [&](int kt) {
        const int k0 = kt * 64;
        #pragma unroll
        for (int i = 0; i < 8; ++i)
            a_reg[i] = *(const f32x4*)(x + (size_t)(m0 + ar + 16 * i) * K_IN + k0 + ac4);
        const int p0 = k0 >> 3;
        #pragma unroll
        for (int i = 0; i < 4; ++i)
            q_reg[i] = qweight[(size_t)(p0 + i * 2 + bph) * N_OUT + ncol];
        const int g = k0 >> 7;
        scale_r = scales[g * N_OUT + ncol];
        const int qz = qzeros[g * (N_OUT / 8) + (ncol >> 3)];
        zs_r = -(float)(((qz >> ((ncol & 7) * 4)) & 0xF) + 1) * scale_r;
    };

    auto store_tile = [&]() {
        #pragma unroll
        for (int i = 0; i < 8; ++i) {
            const int r = ar + 16 * i;
            const int addr = r * 128 + ((ac4 * 2) ^ ((r & 7) << 4));
            union { short4v v; __bf16 h[4]; } u;
            u.h[0] = (__bf16)a_reg[i].x; u.h[1] = (__bf16)a_reg[i].y;
            u.h[2] = (__bf16)a_reg[i].z; u.h[3] = (__bf16)a_reg[i].w;
            *(short4v*)(Ab + addr) = u.v;
        }
        #pragma unroll
        for (int i = 0; i < 4; ++i) {
            const int pl = i * 2 + bph;
            const int q  = q_reg[i];
            union { short8 v; __bf16 h[8]; } u;
            #pragma unroll
            for (int j = 0; j < 8; ++j)
                u.h[j] = (__bf16)fmaf((float)((q >> (4 * j)) & 0xF), scale_r, zs_r);
            const int addr = bnn * 128 + ((pl * 16) ^ ((bnn & 7) << 4));
            *(short8*)(Bb + addr) = u.v;
        }
    };

    auto compute_tile = [&]() {
        #pragma unroll
        for (int kk = 0; kk < 2; ++kk) {
            short8 afr[4], bfr[4];
            const int cb = kk * 64 + (lane >> 4) * 16;
            #pragma unroll
            for (int mi = 0; mi < 4; ++mi) {
                const int r = wm * 64 + mi * 16 + (lane & 15);
                afr[mi] = *(const short8*)(Ab + r * 128 + (cb ^ ((r & 7) << 4)));
            }
            #pragma unroll
            for (int ni = 0; ni < 4; ++ni) {
                const int nn = wn * 64 + ni * 16 + (lane & 15);
                bfr[ni] = *(const short8*)(Bb + nn * 128 + (cb ^ ((nn & 7) << 4)));
            }
            #pragma unroll
            for (int mi = 0; mi < 4; ++mi)
                #pragma unroll
                for (int ni = 0; ni < 4; ++ni)
                    acc[mi][ni] = __builtin_amdgcn_mfma_f32_16x16x32_bf16(
                        afr[mi], bfr[ni], acc[mi][ni], 0, 0, 0);
        }
    };

    load_tile(0);
    for (int kt = 0; kt < 64; ++kt) {
        if (kt) __syncthreads();
        store_tile();
        __syncthreads();
        if (kt + 1 < 64) load_tile(kt + 1);
        compute_tile();
    }

    const int col_base = n0 + wn * 64 + (lane & 15);
    const int row_base = m0 + wm * 64 + (lane >> 4) * 4;
    #pragma unroll
    for (int ni = 0; ni < 4; ++ni) {
        const int col = col_base + ni * 16;
        const float bv = bias[col];
        #pragma unroll
        for (int mi = 0; mi < 4; ++mi)
            #pragma unroll
            for (int r = 0; r < 4; ++r)
                out[(size_t)(row_base + mi * 16 + r) * N_OUT + col] = acc[mi][ni][r] + bv;
    }
}

extern "C" void kernel_launch(void* const* d_in, const int* in_sizes, int n_in,
                              void* d_out, int out_size, void* d_ws, size_t ws_size,
                              hipStream_t stream) {
    const float* x       = (const float*)d_in[0];
    const int*   qweight = (const int*)  d_in[1];
    const int*   qzeros  = (const int*)  d_in[2];
    const float* scales  = (const float*)d_in[3];
    const float* bias    = (const float*)d_in[5];
    float* out = (float*)d_out;

    const size_t xb_bytes = (size_t)M_TOK * K_IN * 2;   // 64 MiB
    const size_t wt_bytes = (size_t)N_OUT * K_IN * 2;   // 32 MiB

    if (ws_size >= xb_bytes + wt_bytes) {
        unsigned short* xb = (unsigned short*)d_ws;
        unsigned short* Wt = (unsigned short*)((char*)d_ws + xb_bytes);
        cvt_x<<<dim3((M_TOK * K_IN) / (256 * 8)), dim3(256), 0, stream>>>(x, xb);
        dequant_w<<<dim3(K_IN / 64, N_OUT / 64), dim3(256), 0, stream>>>(qweight, qzeros, scales, Wt);
        gemm_bf16_occ<<<dim3((M_TOK / 256) * (N_OUT / 128)), dim3(512), 0, stream>>>(xb, Wt, bias, out);
    } else {
        gptq_gemm_fused<<<dim3(N_OUT / 128, M_TOK / 128), dim3(256), 0, stream>>>(
            x, qweight, qzeros, scales, bias, out);
    }
}